// Round 13
// baseline (6392.648 us; speedup 1.0000x reference)
//
#include <hip/hip_runtime.h>
#include <hip/hip_bf16.h>
#include <math.h>

// Problem constants
#define S   2048
#define E   256
#define HD  256
#define NCOL 2048   // 2 dirs * 4 gates * HD
#define NT  48
#define NWG 16      // recurrence workgroups (8 per direction)

// ---------------- workspace layout (bytes) ----------------
#define XZ_OFF      ((size_t)0)                         // float[S][2048]
#define XZ_BYTES    ((size_t)S * 2048 * 4)
#define LSTM_OFF    (XZ_OFF + XZ_BYTES)                 // float[S][512]
#define LSTM_BYTES  ((size_t)S * 512 * 4)
#define FEATS_OFF   (LSTM_OFF + LSTM_BYTES)             // float[S][48]
#define FEATS_BYTES ((size_t)S * NT * 4)
#define HCUR2_OFF   (FEATS_OFF + FEATS_BYTES)           // uint2[2 slot][2 dir][256]
#define HCUR2_BYTES ((size_t)2 * 2 * 256 * 8)
#define BPS_OFF     (HCUR2_OFF + HCUR2_BYTES)           // u8[2048][48]
#define BPS_BYTES   ((size_t)S * NT)
#define PATHA_OFF   (BPS_OFF + BPS_BYTES)               // u8[3072][32]
#define PATHA_BYTES ((size_t)3072 * 32)

// =========================================================
// Device-scope ops (sc0 sc1 = coherence point; proven r5-r12).
// Monolithic poll ONLY: loads + vmcnt(0) inside ONE asm block (split
// polling failed compile in r9 and correctness in r11 — banned).
// =========================================================
__device__ __forceinline__ void st_pair_dev(uint2* p, uint2 v) {
    asm volatile("global_store_dwordx2 %0, %1, off sc0 sc1"
                 :: "v"(p), "v"(v) : "memory");
}

__device__ __forceinline__ bool try_h16(const uint2* p, unsigned want,
                                        float h16[16]) {
    uint4 a, b, c, d, e, f, g, h;
    asm volatile(
        "global_load_dwordx4 %0, %8, off sc0 sc1\n\t"
        "global_load_dwordx4 %1, %8, off offset:16 sc0 sc1\n\t"
        "global_load_dwordx4 %2, %8, off offset:32 sc0 sc1\n\t"
        "global_load_dwordx4 %3, %8, off offset:48 sc0 sc1\n\t"
        "global_load_dwordx4 %4, %8, off offset:64 sc0 sc1\n\t"
        "global_load_dwordx4 %5, %8, off offset:80 sc0 sc1\n\t"
        "global_load_dwordx4 %6, %8, off offset:96 sc0 sc1\n\t"
        "global_load_dwordx4 %7, %8, off offset:112 sc0 sc1\n\t"
        "s_waitcnt vmcnt(0)"
        : "=&v"(a), "=&v"(b), "=&v"(c), "=&v"(d),
          "=&v"(e), "=&v"(f), "=&v"(g), "=&v"(h)
        : "v"(p)
        : "memory");
    const unsigned bad =
        (a.y ^ want) | (a.w ^ want) | (b.y ^ want) | (b.w ^ want) |
        (c.y ^ want) | (c.w ^ want) | (d.y ^ want) | (d.w ^ want) |
        (e.y ^ want) | (e.w ^ want) | (f.y ^ want) | (f.w ^ want) |
        (g.y ^ want) | (g.w ^ want) | (h.y ^ want) | (h.w ^ want);
    if (bad) return false;
    h16[0]  = __uint_as_float(a.x); h16[1]  = __uint_as_float(a.z);
    h16[2]  = __uint_as_float(b.x); h16[3]  = __uint_as_float(b.z);
    h16[4]  = __uint_as_float(c.x); h16[5]  = __uint_as_float(c.z);
    h16[6]  = __uint_as_float(d.x); h16[7]  = __uint_as_float(d.z);
    h16[8]  = __uint_as_float(e.x); h16[9]  = __uint_as_float(e.z);
    h16[10] = __uint_as_float(f.x); h16[11] = __uint_as_float(f.z);
    h16[12] = __uint_as_float(g.x); h16[13] = __uint_as_float(g.z);
    h16[14] = __uint_as_float(h.x); h16[15] = __uint_as_float(h.z);
    return true;
}

// =========================================================
// Kernel 1: xz[t][col] = emb[sent[t]] @ [Wih_f;Wih_b].T + [b_f;b_b]
// (unchanged, proven)
// =========================================================
__global__ __launch_bounds__(256) void gemm_xz(
    const int* __restrict__ sent, const float* __restrict__ emb,
    const float* __restrict__ Wih_f, const float* __restrict__ Wih_b,
    const float* __restrict__ b_f, const float* __restrict__ b_b,
    float* __restrict__ xz)
{
    __shared__ float As[16][132];
    __shared__ float Bs[16][132];
    const int tid = threadIdx.x;
    const int bm = blockIdx.x * 128;   // t tile
    const int bn = blockIdx.y * 128;   // col tile
    const int tx = tid & 15, ty = tid >> 4;
    const int lm = tid >> 1, kq = (tid & 1) * 8;

    const int srow = sent[bm + lm];
    const float* arow = emb + (size_t)srow * E;
    const int bcol = bn + lm;
    const float* brow = (bcol < 1024) ? (Wih_f + (size_t)bcol * E)
                                      : (Wih_b + (size_t)(bcol - 1024) * E);
    float acc[8][8];
#pragma unroll
    for (int i = 0; i < 8; ++i)
#pragma unroll
        for (int j = 0; j < 8; ++j) acc[i][j] = 0.f;

    for (int k0 = 0; k0 < 256; k0 += 16) {
        float4 a0 = *(const float4*)(arow + k0 + kq);
        float4 a1 = *(const float4*)(arow + k0 + kq + 4);
        float4 c0v = *(const float4*)(brow + k0 + kq);
        float4 c1v = *(const float4*)(brow + k0 + kq + 4);
        __syncthreads();
        As[kq + 0][lm] = a0.x; As[kq + 1][lm] = a0.y; As[kq + 2][lm] = a0.z; As[kq + 3][lm] = a0.w;
        As[kq + 4][lm] = a1.x; As[kq + 5][lm] = a1.y; As[kq + 6][lm] = a1.z; As[kq + 7][lm] = a1.w;
        Bs[kq + 0][lm] = c0v.x; Bs[kq + 1][lm] = c0v.y; Bs[kq + 2][lm] = c0v.z; Bs[kq + 3][lm] = c0v.w;
        Bs[kq + 4][lm] = c1v.x; Bs[kq + 5][lm] = c1v.y; Bs[kq + 6][lm] = c1v.z; Bs[kq + 7][lm] = c1v.w;
        __syncthreads();
#pragma unroll
        for (int k = 0; k < 16; ++k) {
            float av[8], bv[8];
            *(float4*)&av[0] = *(const float4*)&As[k][ty * 8];
            *(float4*)&av[4] = *(const float4*)&As[k][ty * 8 + 4];
            *(float4*)&bv[0] = *(const float4*)&Bs[k][tx * 8];
            *(float4*)&bv[4] = *(const float4*)&Bs[k][tx * 8 + 4];
#pragma unroll
            for (int i = 0; i < 8; ++i)
#pragma unroll
                for (int j = 0; j < 8; ++j) acc[i][j] += av[i] * bv[j];
        }
    }
    float bias[8];
    const int cb = bn + tx * 8;
    const float* bptr = (cb < 1024) ? (b_f + cb) : (b_b + cb - 1024);
    *(float4*)&bias[0] = *(const float4*)bptr;
    *(float4*)&bias[4] = *(const float4*)(bptr + 4);
#pragma unroll
    for (int i = 0; i < 8; ++i) {
        const int trow = bm + ty * 8 + i;
        float4 o0, o1;
        o0.x = acc[i][0] + bias[0]; o0.y = acc[i][1] + bias[1];
        o0.z = acc[i][2] + bias[2]; o0.w = acc[i][3] + bias[3];
        o1.x = acc[i][4] + bias[4]; o1.y = acc[i][5] + bias[5];
        o1.z = acc[i][6] + bias[6]; o1.w = acc[i][7] + bias[7];
        *(float4*)(xz + (size_t)trow * NCOL + cb) = o0;
        *(float4*)(xz + (size_t)trow * NCOL + cb + 4) = o1;
    }
}

// =========================================================
// Kernel 2: persistent bidirectional LSTM recurrence, v12.
// r7's proven sync (data-as-flag pairs, monolithic device-scope poll,
// same addresses/counts) with a leaner per-step stage pipeline:
//  - row mapping lr -> (gate = lr&3, unit = lr>>2): a unit's 4 gates
//    land in ADJACENT lanes of the consumer stage.
//  - gate combine via quad shfl_xor(1/2/3) — actb LDS round deleted.
//  - red[] double-buffered by step parity -> ONE __syncthreads/step.
//    (WAR on red[p] is ordered by the poll: write@s+2 <- poll(s+2) <-
//     publish(s+1) <- barrier(s+1) <- reads@s.)
// All z/c/h values bit-identical to r7 (same k-order, same xor tree,
// same combine formula, same gate expressions).
// =========================================================
__global__ void __launch_bounds__(256, 1) lstm_rec(
    const float* __restrict__ Whh_f, const float* __restrict__ Whh_b,
    const float* __restrict__ h0, const float* __restrict__ c0,
    const float* __restrict__ xz, uint2* __restrict__ hcur2,
    float* __restrict__ lstm_out)
{
    __shared__ float red[2][4][16][8];   // [parity][wave][rg][q]
    const int wg = blockIdx.x;
    const int dir = wg >> 3;        // 0 fwd, 1 bwd
    const int wi = wg & 7;          // index within direction
    const int ub = wi * 32;         // first hidden unit owned
    const int tid = threadIdx.x;
    const int kg = tid >> 4;        // 0..15  k-slice (16 wide)
    const int rg = tid & 15;        // 0..15  row group (8 rows each)
    const int k0 = kg * 16;
    const float* Whh = dir ? Whh_b : Whh_f;

    // weights: 8 rows x 16 k. Row lr = rg*8+q -> gate = lr&3, unit = lr>>2
    float w[8][16];
#pragma unroll
    for (int q = 0; q < 8; ++q) {
        const int lr = rg * 8 + q;                      // 0..127
        const int grow = (lr & 3) * 256 + ub + (lr >> 2);
        const float* wr = Whh + (size_t)grow * 256 + k0;
#pragma unroll
        for (int kk = 0; kk < 16; kk += 4) {
            float4 v = *(const float4*)(wr + kk);
            w[q][kk] = v.x; w[q][kk + 1] = v.y; w[q][kk + 2] = v.z; w[q][kk + 3] = v.w;
        }
    }
#pragma unroll
    for (int q = 0; q < 8; ++q)
#pragma unroll
        for (int kk = 0; kk < 16; ++kk)
            asm volatile("" : "+v"(w[q][kk]));

    // consumer-lane roles (tid<128): gate = tid&3, unit u = tid>>2
    const int gate = tid & 3;
    const int uu   = tid >> 2;      // 0..31 for tid<128
    const bool lead = (tid < 128) && (gate == 0);

    float cst = 0.f;
    if (lead) {
        cst = c0[dir * 256 + ub + uu];
        uint2 iv;
        iv.x = __float_as_uint(h0[dir * 256 + ub + uu]);
        iv.y = 0u;
        st_pair_dev(hcur2 + (size_t)dir * 256 + ub + uu, iv);   // slot 0
    }
    // xz col for consumer row lr2 = tid: dir*1024 + gate*256 + ub + u
    const int zcol = dir * 1024 + gate * 256 + ub + uu;

    for (int step = 0; step < S; ++step) {
        const int p = step & 1;
        const int tz = dir ? (S - 1 - step) : step;
        // prefetch input part (plain cached load; overlaps the poll)
        float xzv = 0.f;
        if (tid < 128) xzv = xz[(size_t)tz * NCOL + zcol];

        // poll the data itself: 16 {h, tag} pairs of this k-slice
        const uint2* hb = hcur2 + ((size_t)p * 2 + dir) * 256 + k0;
        float h16[16];
        while (!try_h16(hb, (unsigned)step, h16)) {}

        float acc[8];
#pragma unroll
        for (int q = 0; q < 8; ++q) acc[q] = 0.f;
#pragma unroll
        for (int kk = 0; kk < 16; ++kk)
#pragma unroll
            for (int q = 0; q < 8; ++q) acc[q] += w[q][kk] * h16[kk];
        // butterfly over the 4 k-groups within this wave
#pragma unroll
        for (int q = 0; q < 8; ++q) {
            acc[q] += __shfl_xor(acc[q], 16);
            acc[q] += __shfl_xor(acc[q], 32);
        }
        if ((kg & 3) == 0) {
            const int wv = kg >> 2;
#pragma unroll
            for (int q = 0; q < 8; ++q) red[p][wv][rg][q] = acc[q];
        }
        __syncthreads();
        if (tid < 128) {
            const int rg2 = tid >> 3, q2 = tid & 7;    // row lr2 = tid
            const float z = ((red[p][0][rg2][q2] + red[p][1][rg2][q2]) +
                             (red[p][2][rg2][q2] + red[p][3][rg2][q2])) + xzv;
            const float av = (gate == 2) ? tanhf(z) : (1.f / (1.f + expf(-z)));
            // quad gather: lane 4u holds i; +1 f; +2 g; +3 o
            const float fg = __shfl_xor(av, 1);
            const float gg = __shfl_xor(av, 2);
            const float og = __shfl_xor(av, 3);
            if (gate == 0) {
                cst = fg * cst + av * gg;
                const float h = og * tanhf(cst);
                uint2 pv;
                pv.x = __float_as_uint(h);
                pv.y = (unsigned)(step + 1);
                st_pair_dev(hcur2 + ((size_t)((step + 1) & 1) * 2 + dir) * 256 + ub + uu, pv);
                lstm_out[(size_t)tz * 512 + dir * 256 + ub + uu] = h;   // plain store
            }
        }
    }
}

// =========================================================
// Kernel 3: feats[t][tag] = lstm_out[t] . W_out[tag] + b_out[tag]
// (unchanged, proven)
// =========================================================
__global__ __launch_bounds__(256) void feats_k(
    const float* __restrict__ lstm, const float* __restrict__ Wout,
    const float* __restrict__ bout, float* __restrict__ feats)
{
    const int gid = blockIdx.x * 256 + threadIdx.x;
    if (gid >= S * NT) return;
    const int t = gid / NT, tag = gid - t * NT;
    const float* hr = lstm + (size_t)t * 512;
    const float* wr = Wout + (size_t)tag * 512;
    float s0 = 0, s1 = 0, s2 = 0, s3 = 0;
#pragma unroll 4
    for (int k = 0; k < 512; k += 4) {
        float4 h4 = *(const float4*)(hr + k);
        float4 w4 = *(const float4*)(wr + k);
        s0 += h4.x * w4.x; s1 += h4.y * w4.y;
        s2 += h4.z * w4.z; s3 += h4.w * w4.w;
    }
    feats[gid] = (s0 + s1) + (s2 + s3) + bout[tag];
}

// =========================================================
// Kernel 4: Viterbi — r2/r7 PROVEN structure verbatim (r12's streaming
// single-wave forward was ~1.65 ms vs this version's ~1.2 ms; the
// 192-thread layout wins — reverted permanently).
// =========================================================
__global__ void __launch_bounds__(256, 1) viterbi_k(
    const float* __restrict__ feats, const float* __restrict__ trans,
    unsigned char* __restrict__ bps, unsigned char* __restrict__ pathA,
    int* __restrict__ out)
{
    __shared__ float v2[2][NT];
    __shared__ unsigned char cmap[64][NT];
    __shared__ int SB[65];
    __shared__ int last_s;
    const int tid = threadIdx.x;
    const int j = tid >> 2, ig = tid & 3;
    const bool act = (tid < 192);

    float Treg[12];
    if (act) {
#pragma unroll
        for (int r = 0; r < 12; ++r) Treg[r] = trans[(ig * 12 + r) * NT + j];
    }
    if (tid < NT) v2[0][tid] = feats[tid];
    __syncthreads();

    float obs_c = 0.f;
    if (act) obs_c = feats[NT + j];
    for (int t = 1; t < S; ++t) {
        float obs_n = 0.f;
        if (act && t < S - 1) obs_n = feats[(size_t)(t + 1) * NT + j];
        const int p = (t - 1) & 1;
        if (act) {
            float best = -1e30f; int bi = 0;
#pragma unroll
            for (int r = 0; r < 12; ++r) {
                const int i = ig * 12 + r;
                const float sc = (v2[p][i] + Treg[r]) + obs_c;
                if (sc > best) { best = sc; bi = i; }
            }
            // reduce across the 4 i-groups; first-index wins ties
            {
                float ob = __shfl_xor(best, 1); int obi = __shfl_xor(bi, 1);
                if (ob > best || (ob == best && obi < bi)) { best = ob; bi = obi; }
                ob = __shfl_xor(best, 2); obi = __shfl_xor(bi, 2);
                if (ob > best || (ob == best && obi < bi)) { best = ob; bi = obi; }
            }
            if (ig == 0) {
                v2[p ^ 1][j] = best;
                bps[(size_t)(t - 1) * NT + j] = (unsigned char)bi;
            }
        }
        __syncthreads();
        obs_c = obs_n;
    }
    if (tid == 0) {
        float b = -1e30f; int bi = 0;
        for (int q = 0; q < NT; ++q) { if (v2[1][q] > b) { b = v2[1][q]; bi = q; } }
        last_s = bi;
    }
    // Phase A: 64 chunks x 48 states, 12 tasks/thread, ILP-12 chains
    int cArr[12], sArr[12];
    unsigned char stv[12];
#pragma unroll
    for (int r = 0; r < 12; ++r) {
        const int task = r * 256 + tid;
        cArr[r] = task / NT;
        sArr[r] = task - cArr[r] * NT;
        stv[r] = (unsigned char)sArr[r];
    }
    for (int stp = 31; stp >= 0; --stp) {
#pragma unroll
        for (int r = 0; r < 12; ++r) {
            const int km = cArr[r] * 32 + stp;
            if (km < S - 1) stv[r] = bps[(size_t)km * NT + stv[r]];
            pathA[(size_t)(cArr[r] * NT + sArr[r]) * 32 + stp] = stv[r];
        }
    }
#pragma unroll
    for (int r = 0; r < 12; ++r) cmap[cArr[r]][sArr[r]] = stv[r];
    __syncthreads();
    if (tid == 0) {
        SB[64] = last_s;
        for (int c = 63; c >= 0; --c) SB[c] = cmap[c][SB[c + 1]];
    }
    __syncthreads();
    for (int t = tid; t < S; t += 256) {
        const int c = t >> 5;
        out[t] = (int)pathA[(size_t)(c * NT + SB[c + 1]) * 32 + (t & 31)];
    }
}

// =========================================================
extern "C" void kernel_launch(void* const* d_in, const int* in_sizes, int n_in,
                              void* d_out, int out_size, void* d_ws, size_t ws_size,
                              hipStream_t stream) {
    const int*   sent   = (const int*)d_in[0];
    const float* emb    = (const float*)d_in[1];
    const float* Wih_f  = (const float*)d_in[2];
    const float* Whh_f  = (const float*)d_in[3];
    const float* b_f    = (const float*)d_in[4];
    const float* Wih_b  = (const float*)d_in[5];
    const float* Whh_b  = (const float*)d_in[6];
    const float* b_b    = (const float*)d_in[7];
    const float* W_out  = (const float*)d_in[8];
    const float* b_out  = (const float*)d_in[9];
    const float* trans  = (const float*)d_in[10];
    const float* h0     = (const float*)d_in[11];
    const float* c0     = (const float*)d_in[12];
    int* out = (int*)d_out;

    char* ws = (char*)d_ws;
    float* xz       = (float*)(ws + XZ_OFF);
    float* lstm     = (float*)(ws + LSTM_OFF);
    float* feats    = (float*)(ws + FEATS_OFF);
    uint2* hcur2    = (uint2*)(ws + HCUR2_OFF);
    unsigned char* bps   = (unsigned char*)(ws + BPS_OFF);
    unsigned char* pathA = (unsigned char*)(ws + PATHA_OFF);

    // reset tags so no stale {h, tag} pair from a previous replay can
    // alias a wanted tag (tags are exact-match, 0..2048)
    hipMemsetAsync(hcur2, 0xFF, HCUR2_BYTES, stream);

    gemm_xz<<<dim3(16, 16), 256, 0, stream>>>(sent, emb, Wih_f, Wih_b, b_f, b_b, xz);

    lstm_rec<<<dim3(NWG), 256, 0, stream>>>(Whh_f, Whh_b, h0, c0, xz, hcur2, lstm);

    feats_k<<<dim3((S * NT + 255) / 256), 256, 0, stream>>>(lstm, W_out, b_out, feats);

    viterbi_k<<<dim3(1), 256, 0, stream>>>(feats, trans, bps, pathA, out);
}

// Round 14
// 5502.559 us; speedup vs baseline: 1.1618x; 1.1618x over previous
//
#include <hip/hip_runtime.h>
#include <hip/hip_bf16.h>
#include <math.h>

// Problem constants
#define S   2048
#define E   256
#define HD  256
#define NCOL 2048   // 2 dirs * 4 gates * HD
#define NT  48
#define NWG 16      // recurrence workgroups (8 per direction)

// ---------------- workspace layout (bytes) ----------------
#define XZ_OFF      ((size_t)0)                         // float[S][2048]
#define XZ_BYTES    ((size_t)S * 2048 * 4)
#define LSTM_OFF    (XZ_OFF + XZ_BYTES)                 // float[S][512]
#define LSTM_BYTES  ((size_t)S * 512 * 4)
#define FEATS_OFF   (LSTM_OFF + LSTM_BYTES)             // float[S][48]
#define FEATS_BYTES ((size_t)S * NT * 4)
#define HCUR2_OFF   (FEATS_OFF + FEATS_BYTES)           // uint2[2 slot][2 dir][256]
#define HCUR2_BYTES ((size_t)2 * 2 * 256 * 8)
#define BPS_OFF     (HCUR2_OFF + HCUR2_BYTES)           // u8[2048][48]
#define BPS_BYTES   ((size_t)S * NT)
#define PATHA_OFF   (BPS_OFF + BPS_BYTES)               // u8[3072][32]
#define PATHA_BYTES ((size_t)3072 * 32)

// =========================================================
// Device-scope ops (sc0 sc1 = coherence point; proven r5-r13).
// Monolithic poll ONLY: loads + vmcnt(0) inside ONE asm block (split
// polling failed compile in r9 and correctness in r11 — banned).
// =========================================================
__device__ __forceinline__ void st_pair_dev(uint2* p, uint2 v) {
    asm volatile("global_store_dwordx2 %0, %1, off sc0 sc1"
                 :: "v"(p), "v"(v) : "memory");
}

__device__ __forceinline__ bool try_h16(const uint2* p, unsigned want,
                                        float h16[16]) {
    uint4 a, b, c, d, e, f, g, h;
    asm volatile(
        "global_load_dwordx4 %0, %8, off sc0 sc1\n\t"
        "global_load_dwordx4 %1, %8, off offset:16 sc0 sc1\n\t"
        "global_load_dwordx4 %2, %8, off offset:32 sc0 sc1\n\t"
        "global_load_dwordx4 %3, %8, off offset:48 sc0 sc1\n\t"
        "global_load_dwordx4 %4, %8, off offset:64 sc0 sc1\n\t"
        "global_load_dwordx4 %5, %8, off offset:80 sc0 sc1\n\t"
        "global_load_dwordx4 %6, %8, off offset:96 sc0 sc1\n\t"
        "global_load_dwordx4 %7, %8, off offset:112 sc0 sc1\n\t"
        "s_waitcnt vmcnt(0)"
        : "=&v"(a), "=&v"(b), "=&v"(c), "=&v"(d),
          "=&v"(e), "=&v"(f), "=&v"(g), "=&v"(h)
        : "v"(p)
        : "memory");
    const unsigned bad =
        (a.y ^ want) | (a.w ^ want) | (b.y ^ want) | (b.w ^ want) |
        (c.y ^ want) | (c.w ^ want) | (d.y ^ want) | (d.w ^ want) |
        (e.y ^ want) | (e.w ^ want) | (f.y ^ want) | (f.w ^ want) |
        (g.y ^ want) | (g.w ^ want) | (h.y ^ want) | (h.w ^ want);
    if (bad) return false;
    h16[0]  = __uint_as_float(a.x); h16[1]  = __uint_as_float(a.z);
    h16[2]  = __uint_as_float(b.x); h16[3]  = __uint_as_float(b.z);
    h16[4]  = __uint_as_float(c.x); h16[5]  = __uint_as_float(c.z);
    h16[6]  = __uint_as_float(d.x); h16[7]  = __uint_as_float(d.z);
    h16[8]  = __uint_as_float(e.x); h16[9]  = __uint_as_float(e.z);
    h16[10] = __uint_as_float(f.x); h16[11] = __uint_as_float(f.z);
    h16[12] = __uint_as_float(g.x); h16[13] = __uint_as_float(g.z);
    h16[14] = __uint_as_float(h.x); h16[15] = __uint_as_float(h.z);
    return true;
}

// =========================================================
// Kernel 1: xz[t][col] = emb[sent[t]] @ [Wih_f;Wih_b].T + [b_f;b_b]
// (unchanged, proven)
// =========================================================
__global__ __launch_bounds__(256) void gemm_xz(
    const int* __restrict__ sent, const float* __restrict__ emb,
    const float* __restrict__ Wih_f, const float* __restrict__ Wih_b,
    const float* __restrict__ b_f, const float* __restrict__ b_b,
    float* __restrict__ xz)
{
    __shared__ float As[16][132];
    __shared__ float Bs[16][132];
    const int tid = threadIdx.x;
    const int bm = blockIdx.x * 128;   // t tile
    const int bn = blockIdx.y * 128;   // col tile
    const int tx = tid & 15, ty = tid >> 4;
    const int lm = tid >> 1, kq = (tid & 1) * 8;

    const int srow = sent[bm + lm];
    const float* arow = emb + (size_t)srow * E;
    const int bcol = bn + lm;
    const float* brow = (bcol < 1024) ? (Wih_f + (size_t)bcol * E)
                                      : (Wih_b + (size_t)(bcol - 1024) * E);
    float acc[8][8];
#pragma unroll
    for (int i = 0; i < 8; ++i)
#pragma unroll
        for (int j = 0; j < 8; ++j) acc[i][j] = 0.f;

    for (int k0 = 0; k0 < 256; k0 += 16) {
        float4 a0 = *(const float4*)(arow + k0 + kq);
        float4 a1 = *(const float4*)(arow + k0 + kq + 4);
        float4 c0v = *(const float4*)(brow + k0 + kq);
        float4 c1v = *(const float4*)(brow + k0 + kq + 4);
        __syncthreads();
        As[kq + 0][lm] = a0.x; As[kq + 1][lm] = a0.y; As[kq + 2][lm] = a0.z; As[kq + 3][lm] = a0.w;
        As[kq + 4][lm] = a1.x; As[kq + 5][lm] = a1.y; As[kq + 6][lm] = a1.z; As[kq + 7][lm] = a1.w;
        Bs[kq + 0][lm] = c0v.x; Bs[kq + 1][lm] = c0v.y; Bs[kq + 2][lm] = c0v.z; Bs[kq + 3][lm] = c0v.w;
        Bs[kq + 4][lm] = c1v.x; Bs[kq + 5][lm] = c1v.y; Bs[kq + 6][lm] = c1v.z; Bs[kq + 7][lm] = c1v.w;
        __syncthreads();
#pragma unroll
        for (int k = 0; k < 16; ++k) {
            float av[8], bv[8];
            *(float4*)&av[0] = *(const float4*)&As[k][ty * 8];
            *(float4*)&av[4] = *(const float4*)&As[k][ty * 8 + 4];
            *(float4*)&bv[0] = *(const float4*)&Bs[k][tx * 8];
            *(float4*)&bv[4] = *(const float4*)&Bs[k][tx * 8 + 4];
#pragma unroll
            for (int i = 0; i < 8; ++i)
#pragma unroll
                for (int j = 0; j < 8; ++j) acc[i][j] += av[i] * bv[j];
        }
    }
    float bias[8];
    const int cb = bn + tx * 8;
    const float* bptr = (cb < 1024) ? (b_f + cb) : (b_b + cb - 1024);
    *(float4*)&bias[0] = *(const float4*)bptr;
    *(float4*)&bias[4] = *(const float4*)(bptr + 4);
#pragma unroll
    for (int i = 0; i < 8; ++i) {
        const int trow = bm + ty * 8 + i;
        float4 o0, o1;
        o0.x = acc[i][0] + bias[0]; o0.y = acc[i][1] + bias[1];
        o0.z = acc[i][2] + bias[2]; o0.w = acc[i][3] + bias[3];
        o1.x = acc[i][4] + bias[4]; o1.y = acc[i][5] + bias[5];
        o1.z = acc[i][6] + bias[6]; o1.w = acc[i][7] + bias[7];
        *(float4*)(xz + (size_t)trow * NCOL + cb) = o0;
        *(float4*)(xz + (size_t)trow * NCOL + cb + 4) = o1;
    }
}

// =========================================================
// Kernel 2: persistent bidirectional LSTM recurrence — round-7 proven
// version VERBATIM (best measured: 4077 us). 16 WGs x 256 thr, fixed
// roles, data-as-flag {h,tag} pairs, monolithic device-scope poll.
// Frozen: r12 (launch_bounds) and r13 (stage fusion) both showed the
// poll RTT dominates; compute-side tweaks are noise or regressions.
// =========================================================
__global__ void __launch_bounds__(256, 2) lstm_rec(
    const float* __restrict__ Whh_f, const float* __restrict__ Whh_b,
    const float* __restrict__ h0, const float* __restrict__ c0,
    const float* __restrict__ xz, uint2* __restrict__ hcur2,
    float* __restrict__ lstm_out)
{
    __shared__ float red[4][16][8];
    __shared__ float actb[128];
    const int wg = blockIdx.x;
    const int dir = wg >> 3;        // 0 fwd, 1 bwd
    const int wi = wg & 7;          // index within direction
    const int ub = wi * 32;         // first hidden unit owned
    const int tid = threadIdx.x;
    const int kg = tid >> 4;        // 0..15  k-slice (16 wide)
    const int rg = tid & 15;        // 0..15  row group (8 rows each)
    const int k0 = kg * 16;
    const float* Whh = dir ? Whh_b : Whh_f;

    // load weights into registers: 8 rows x 16 k
    float w[8][16];
#pragma unroll
    for (int q = 0; q < 8; ++q) {
        const int lr = rg * 8 + q;                      // 0..127
        const int grow = (lr >> 5) * 256 + ub + (lr & 31);
        const float* wr = Whh + (size_t)grow * 256 + k0;
#pragma unroll
        for (int kk = 0; kk < 16; kk += 4) {
            float4 v = *(const float4*)(wr + kk);
            w[q][kk] = v.x; w[q][kk + 1] = v.y; w[q][kk + 2] = v.z; w[q][kk + 3] = v.w;
        }
    }
#pragma unroll
    for (int q = 0; q < 8; ++q)
#pragma unroll
        for (int kk = 0; kk < 16; ++kk)
            asm volatile("" : "+v"(w[q][kk]));   // keep register-resident

    // seed cell state and {h0, tag=0} for this WG's own units
    float cst = 0.f;
    if (tid < 32) {
        cst = c0[dir * 256 + ub + tid];
        uint2 iv;
        iv.x = __float_as_uint(h0[dir * 256 + ub + tid]);
        iv.y = 0u;
        st_pair_dev(hcur2 + (size_t)dir * 256 + ub + tid, iv);   // slot 0
    }
    // z-row mapping for tid<128: row = tid -> gate=tid>>5, unit=tid&31
    const int zcol = dir * 1024 + (tid >> 5) * 256 + ub + (tid & 31);

    for (int step = 0; step < S; ++step) {
        // prefetch input part (plain cached load; overlaps the poll)
        float xzv = 0.f;
        if (tid < 128) {
            const int tz = dir ? (S - 1 - step) : step;
            xzv = xz[(size_t)tz * NCOL + zcol];
        }
        // poll the data itself: 16 {h, tag} pairs of this k-slice
        const uint2* hb = hcur2 + ((size_t)(step & 1) * 2 + dir) * 256 + k0;
        float h16[16];
        while (!try_h16(hb, (unsigned)step, h16)) {}

        float acc[8];
#pragma unroll
        for (int q = 0; q < 8; ++q) acc[q] = 0.f;
#pragma unroll
        for (int kk = 0; kk < 16; ++kk)
#pragma unroll
            for (int q = 0; q < 8; ++q) acc[q] += w[q][kk] * h16[kk];
        // butterfly over the 4 k-groups within this wave
#pragma unroll
        for (int q = 0; q < 8; ++q) {
            acc[q] += __shfl_xor(acc[q], 16);
            acc[q] += __shfl_xor(acc[q], 32);
        }
        if ((kg & 3) == 0) {
            const int wv = kg >> 2;
#pragma unroll
            for (int q = 0; q < 8; ++q) red[wv][rg][q] = acc[q];
        }
        __syncthreads();
        if (tid < 128) {
            const int rg2 = tid >> 3, q2 = tid & 7;
            const float z = ((red[0][rg2][q2] + red[1][rg2][q2]) +
                             (red[2][rg2][q2] + red[3][rg2][q2])) + xzv;
            const int gate = tid >> 5;
            actb[tid] = (gate == 2) ? tanhf(z) : (1.f / (1.f + expf(-z)));
        }
        __syncthreads();
        if (tid < 32) {
            const int u = tid;
            const float ig = actb[u];
            const float fg = actb[32 + u];
            const float gg = actb[64 + u];
            const float og = actb[96 + u];
            cst = fg * cst + ig * gg;
            const float h = og * tanhf(cst);
            const int tz = dir ? (S - 1 - step) : step;
            uint2 pv;
            pv.x = __float_as_uint(h);
            pv.y = (unsigned)(step + 1);
            st_pair_dev(hcur2 + ((size_t)((step + 1) & 1) * 2 + dir) * 256 + ub + u, pv);
            lstm_out[(size_t)tz * 512 + dir * 256 + ub + u] = h;   // plain store
        }
    }
}

// =========================================================
// Kernel 3: feats[t][tag] = lstm_out[t] . W_out[tag] + b_out[tag]
// (unchanged, proven)
// =========================================================
__global__ __launch_bounds__(256) void feats_k(
    const float* __restrict__ lstm, const float* __restrict__ Wout,
    const float* __restrict__ bout, float* __restrict__ feats)
{
    const int gid = blockIdx.x * 256 + threadIdx.x;
    if (gid >= S * NT) return;
    const int t = gid / NT, tag = gid - t * NT;
    const float* hr = lstm + (size_t)t * 512;
    const float* wr = Wout + (size_t)tag * 512;
    float s0 = 0, s1 = 0, s2 = 0, s3 = 0;
#pragma unroll 4
    for (int k = 0; k < 512; k += 4) {
        float4 h4 = *(const float4*)(hr + k);
        float4 w4 = *(const float4*)(wr + k);
        s0 += h4.x * w4.x; s1 += h4.y * w4.y;
        s2 += h4.z * w4.z; s3 += h4.w * w4.w;
    }
    feats[gid] = (s0 + s1) + (s2 + s3) + bout[tag];
}

// =========================================================
// Kernel 4: Viterbi, v4 forward: SINGLE WAVE, ZERO LDS, ZERO BARRIER.
// Lane j (j<48) holds its trans column T[48] in registers (fully
// static unroll indexing -> ~60 live regs, no r5-style spill) and
// v[j] in a register. Cross-lane v broadcast via __shfl with
// compile-time lane index (v_readlane -> SGPR broadcast; wave
// lockstep replaces __syncthreads). 4 ILP chains over ascending
// i-ranges, strict > -> exact reference fp order (v[i]+T[i,j])+obs[j]
// and first-index ties (same per-element formula as the proven r2
// kernel; max reordering is value-exact). Then the proven 256-thread
// chunked backtrack (other 3 waves join at the post-loop barrier).
// =========================================================
__global__ void __launch_bounds__(256, 1) viterbi_k(
    const float* __restrict__ feats, const float* __restrict__ trans,
    unsigned char* __restrict__ bps, unsigned char* __restrict__ pathA,
    int* __restrict__ out)
{
    __shared__ unsigned char cmap[64][NT];
    __shared__ int SB[65];
    __shared__ int last_s;
    const int tid = threadIdx.x;

    if (tid < 64) {
        const bool actj = tid < NT;
        const int j = actj ? tid : 0;
        // trans column in registers (static indices only)
        float T[NT];
#pragma unroll
        for (int i = 0; i < NT; ++i) T[i] = trans[i * NT + j];
        float vself = feats[j];            // v at t=0
        float obs = feats[NT + j];         // obs at t=1
        for (int t = 1; t < S; ++t) {
            const float obs_n = (t < S - 1) ? feats[(size_t)(t + 1) * NT + j] : 0.f;
            float b0 = -1e30f, b1 = -1e30f, b2 = -1e30f, b3 = -1e30f;
            int i0 = 0, i1 = 12, i2 = 24, i3 = 36;
#pragma unroll
            for (int r = 0; r < 12; ++r) {
                const float v0 = __shfl(vself, r);
                const float v1 = __shfl(vself, 12 + r);
                const float v2 = __shfl(vself, 24 + r);
                const float v3 = __shfl(vself, 36 + r);
                const float s0 = (v0 + T[r])      + obs;
                const float s1 = (v1 + T[12 + r]) + obs;
                const float s2 = (v2 + T[24 + r]) + obs;
                const float s3 = (v3 + T[36 + r]) + obs;
                if (s0 > b0) { b0 = s0; i0 = r; }
                if (s1 > b1) { b1 = s1; i1 = 12 + r; }
                if (s2 > b2) { b2 = s2; i2 = 24 + r; }
                if (s3 > b3) { b3 = s3; i3 = 36 + r; }
            }
            // combine ascending; strict > keeps the earlier index on ties
            float best = b0; int bi = i0;
            if (b1 > best) { best = b1; bi = i1; }
            if (b2 > best) { best = b2; bi = i2; }
            if (b3 > best) { best = b3; bi = i3; }

            if (actj) {
                bps[(size_t)(t - 1) * NT + j] = (unsigned char)bi;
                vself = best;
            }
            obs = obs_n;
        }
        // final argmax across lanes (first occurrence), via readlane
        {
            float b = __shfl(vself, 0); int bi = 0;
#pragma unroll
            for (int q = 1; q < NT; ++q) {
                const float vq = __shfl(vself, q);
                if (vq > b) { b = vq; bi = q; }
            }
            if (tid == 0) last_s = bi;
        }
    }
    __syncthreads();

    // Phase A: 64 chunks x 48 states, 12 tasks/thread, ILP-12 chains
    int cArr[12], sArr[12];
    unsigned char stv[12];
#pragma unroll
    for (int r = 0; r < 12; ++r) {
        const int task = r * 256 + tid;
        cArr[r] = task / NT;
        sArr[r] = task - cArr[r] * NT;
        stv[r] = (unsigned char)sArr[r];
    }
    for (int stp = 31; stp >= 0; --stp) {
#pragma unroll
        for (int r = 0; r < 12; ++r) {
            const int km = cArr[r] * 32 + stp;
            if (km < S - 1) stv[r] = bps[(size_t)km * NT + stv[r]];
            pathA[(size_t)(cArr[r] * NT + sArr[r]) * 32 + stp] = stv[r];
        }
    }
#pragma unroll
    for (int r = 0; r < 12; ++r) cmap[cArr[r]][sArr[r]] = stv[r];
    __syncthreads();
    if (tid == 0) {
        SB[64] = last_s;
        for (int c = 63; c >= 0; --c) SB[c] = cmap[c][SB[c + 1]];
    }
    __syncthreads();
    for (int t = tid; t < S; t += 256) {
        const int c = t >> 5;
        out[t] = (int)pathA[(size_t)(c * NT + SB[c + 1]) * 32 + (t & 31)];
    }
}

// =========================================================
extern "C" void kernel_launch(void* const* d_in, const int* in_sizes, int n_in,
                              void* d_out, int out_size, void* d_ws, size_t ws_size,
                              hipStream_t stream) {
    const int*   sent   = (const int*)d_in[0];
    const float* emb    = (const float*)d_in[1];
    const float* Wih_f  = (const float*)d_in[2];
    const float* Whh_f  = (const float*)d_in[3];
    const float* b_f    = (const float*)d_in[4];
    const float* Wih_b  = (const float*)d_in[5];
    const float* Whh_b  = (const float*)d_in[6];
    const float* b_b    = (const float*)d_in[7];
    const float* W_out  = (const float*)d_in[8];
    const float* b_out  = (const float*)d_in[9];
    const float* trans  = (const float*)d_in[10];
    const float* h0     = (const float*)d_in[11];
    const float* c0     = (const float*)d_in[12];
    int* out = (int*)d_out;

    char* ws = (char*)d_ws;
    float* xz       = (float*)(ws + XZ_OFF);
    float* lstm     = (float*)(ws + LSTM_OFF);
    float* feats    = (float*)(ws + FEATS_OFF);
    uint2* hcur2    = (uint2*)(ws + HCUR2_OFF);
    unsigned char* bps   = (unsigned char*)(ws + BPS_OFF);
    unsigned char* pathA = (unsigned char*)(ws + PATHA_OFF);

    // reset tags so no stale {h, tag} pair from a previous replay can
    // alias a wanted tag (tags are exact-match, 0..2048)
    hipMemsetAsync(hcur2, 0xFF, HCUR2_BYTES, stream);

    gemm_xz<<<dim3(16, 16), 256, 0, stream>>>(sent, emb, Wih_f, Wih_b, b_f, b_b, xz);

    lstm_rec<<<dim3(NWG), 256, 0, stream>>>(Whh_f, Whh_b, h0, c0, xz, hcur2, lstm);

    feats_k<<<dim3((S * NT + 255) / 256), 256, 0, stream>>>(lstm, W_out, b_out, feats);

    viterbi_k<<<dim3(1), 256, 0, stream>>>(feats, trans, bps, pathA, out);
}

// Round 15
// 5367.383 us; speedup vs baseline: 1.1910x; 1.0252x over previous
//
#include <hip/hip_runtime.h>
#include <hip/hip_bf16.h>
#include <math.h>

// Problem constants
#define S   2048
#define E   256
#define HD  256
#define NCOL 2048   // 2 dirs * 4 gates * HD
#define NT  48
#define NWG 16      // recurrence workgroups (8 per direction)

// ---------------- workspace layout (bytes) ----------------
#define XZ_OFF      ((size_t)0)                         // float[S][2048]
#define XZ_BYTES    ((size_t)S * 2048 * 4)
#define LSTM_OFF    (XZ_OFF + XZ_BYTES)                 // float[S][512]
#define LSTM_BYTES  ((size_t)S * 512 * 4)
#define FEATS_OFF   (LSTM_OFF + LSTM_BYTES)             // float[S][48]
#define FEATS_BYTES ((size_t)S * NT * 4)
#define HCUR2_OFF   (FEATS_OFF + FEATS_BYTES)           // uint2[2 slot][2 dir][256]
#define HCUR2_BYTES ((size_t)2 * 2 * 256 * 8)
#define BPS_OFF     (HCUR2_OFF + HCUR2_BYTES)           // u8[2048][48]
#define BPS_BYTES   ((size_t)S * NT)
#define PATHA_OFF   (BPS_OFF + BPS_BYTES)               // u8[3072][32]
#define PATHA_BYTES ((size_t)3072 * 32)

// =========================================================
// Device-scope ops (sc0 sc1 = coherence point; proven r5-r14).
// Monolithic poll ONLY: loads + vmcnt(0) inside ONE asm block (split
// polling failed compile in r9 and correctness in r11 — banned).
// =========================================================
__device__ __forceinline__ void st_pair_dev(uint2* p, uint2 v) {
    asm volatile("global_store_dwordx2 %0, %1, off sc0 sc1"
                 :: "v"(p), "v"(v) : "memory");
}

__device__ __forceinline__ bool try_h16(const uint2* p, unsigned want,
                                        float h16[16]) {
    uint4 a, b, c, d, e, f, g, h;
    asm volatile(
        "global_load_dwordx4 %0, %8, off sc0 sc1\n\t"
        "global_load_dwordx4 %1, %8, off offset:16 sc0 sc1\n\t"
        "global_load_dwordx4 %2, %8, off offset:32 sc0 sc1\n\t"
        "global_load_dwordx4 %3, %8, off offset:48 sc0 sc1\n\t"
        "global_load_dwordx4 %4, %8, off offset:64 sc0 sc1\n\t"
        "global_load_dwordx4 %5, %8, off offset:80 sc0 sc1\n\t"
        "global_load_dwordx4 %6, %8, off offset:96 sc0 sc1\n\t"
        "global_load_dwordx4 %7, %8, off offset:112 sc0 sc1\n\t"
        "s_waitcnt vmcnt(0)"
        : "=&v"(a), "=&v"(b), "=&v"(c), "=&v"(d),
          "=&v"(e), "=&v"(f), "=&v"(g), "=&v"(h)
        : "v"(p)
        : "memory");
    const unsigned bad =
        (a.y ^ want) | (a.w ^ want) | (b.y ^ want) | (b.w ^ want) |
        (c.y ^ want) | (c.w ^ want) | (d.y ^ want) | (d.w ^ want) |
        (e.y ^ want) | (e.w ^ want) | (f.y ^ want) | (f.w ^ want) |
        (g.y ^ want) | (g.w ^ want) | (h.y ^ want) | (h.w ^ want);
    if (bad) return false;
    h16[0]  = __uint_as_float(a.x); h16[1]  = __uint_as_float(a.z);
    h16[2]  = __uint_as_float(b.x); h16[3]  = __uint_as_float(b.z);
    h16[4]  = __uint_as_float(c.x); h16[5]  = __uint_as_float(c.z);
    h16[6]  = __uint_as_float(d.x); h16[7]  = __uint_as_float(d.z);
    h16[8]  = __uint_as_float(e.x); h16[9]  = __uint_as_float(e.z);
    h16[10] = __uint_as_float(f.x); h16[11] = __uint_as_float(f.z);
    h16[12] = __uint_as_float(g.x); h16[13] = __uint_as_float(g.z);
    h16[14] = __uint_as_float(h.x); h16[15] = __uint_as_float(h.z);
    return true;
}

// =========================================================
// Kernel 1: xz[t][col] = emb[sent[t]] @ [Wih_f;Wih_b].T + [b_f;b_b]
// (unchanged, proven)
// =========================================================
__global__ __launch_bounds__(256) void gemm_xz(
    const int* __restrict__ sent, const float* __restrict__ emb,
    const float* __restrict__ Wih_f, const float* __restrict__ Wih_b,
    const float* __restrict__ b_f, const float* __restrict__ b_b,
    float* __restrict__ xz)
{
    __shared__ float As[16][132];
    __shared__ float Bs[16][132];
    const int tid = threadIdx.x;
    const int bm = blockIdx.x * 128;   // t tile
    const int bn = blockIdx.y * 128;   // col tile
    const int tx = tid & 15, ty = tid >> 4;
    const int lm = tid >> 1, kq = (tid & 1) * 8;

    const int srow = sent[bm + lm];
    const float* arow = emb + (size_t)srow * E;
    const int bcol = bn + lm;
    const float* brow = (bcol < 1024) ? (Wih_f + (size_t)bcol * E)
                                      : (Wih_b + (size_t)(bcol - 1024) * E);
    float acc[8][8];
#pragma unroll
    for (int i = 0; i < 8; ++i)
#pragma unroll
        for (int j = 0; j < 8; ++j) acc[i][j] = 0.f;

    for (int k0 = 0; k0 < 256; k0 += 16) {
        float4 a0 = *(const float4*)(arow + k0 + kq);
        float4 a1 = *(const float4*)(arow + k0 + kq + 4);
        float4 c0v = *(const float4*)(brow + k0 + kq);
        float4 c1v = *(const float4*)(brow + k0 + kq + 4);
        __syncthreads();
        As[kq + 0][lm] = a0.x; As[kq + 1][lm] = a0.y; As[kq + 2][lm] = a0.z; As[kq + 3][lm] = a0.w;
        As[kq + 4][lm] = a1.x; As[kq + 5][lm] = a1.y; As[kq + 6][lm] = a1.z; As[kq + 7][lm] = a1.w;
        Bs[kq + 0][lm] = c0v.x; Bs[kq + 1][lm] = c0v.y; Bs[kq + 2][lm] = c0v.z; Bs[kq + 3][lm] = c0v.w;
        Bs[kq + 4][lm] = c1v.x; Bs[kq + 5][lm] = c1v.y; Bs[kq + 6][lm] = c1v.z; Bs[kq + 7][lm] = c1v.w;
        __syncthreads();
#pragma unroll
        for (int k = 0; k < 16; ++k) {
            float av[8], bv[8];
            *(float4*)&av[0] = *(const float4*)&As[k][ty * 8];
            *(float4*)&av[4] = *(const float4*)&As[k][ty * 8 + 4];
            *(float4*)&bv[0] = *(const float4*)&Bs[k][tx * 8];
            *(float4*)&bv[4] = *(const float4*)&Bs[k][tx * 8 + 4];
#pragma unroll
            for (int i = 0; i < 8; ++i)
#pragma unroll
                for (int j = 0; j < 8; ++j) acc[i][j] += av[i] * bv[j];
        }
    }
    float bias[8];
    const int cb = bn + tx * 8;
    const float* bptr = (cb < 1024) ? (b_f + cb) : (b_b + cb - 1024);
    *(float4*)&bias[0] = *(const float4*)bptr;
    *(float4*)&bias[4] = *(const float4*)(bptr + 4);
#pragma unroll
    for (int i = 0; i < 8; ++i) {
        const int trow = bm + ty * 8 + i;
        float4 o0, o1;
        o0.x = acc[i][0] + bias[0]; o0.y = acc[i][1] + bias[1];
        o0.z = acc[i][2] + bias[2]; o0.w = acc[i][3] + bias[3];
        o1.x = acc[i][4] + bias[4]; o1.y = acc[i][5] + bias[5];
        o1.z = acc[i][6] + bias[6]; o1.w = acc[i][7] + bias[7];
        *(float4*)(xz + (size_t)trow * NCOL + cb) = o0;
        *(float4*)(xz + (size_t)trow * NCOL + cb + 4) = o1;
    }
}

// =========================================================
// Kernel 2: persistent bidirectional LSTM recurrence — round-7 proven
// version VERBATIM (measured 3983-4077 us). FROZEN: r12 launch-bounds
// and r13 stage-fusion both showed the device-scope poll RTT dominates;
// compute-side tweaks are noise or regressions. Same-XCD L2 sync
// hanged twice (r4, r8) — banned.
// =========================================================
__global__ void __launch_bounds__(256, 2) lstm_rec(
    const float* __restrict__ Whh_f, const float* __restrict__ Whh_b,
    const float* __restrict__ h0, const float* __restrict__ c0,
    const float* __restrict__ xz, uint2* __restrict__ hcur2,
    float* __restrict__ lstm_out)
{
    __shared__ float red[4][16][8];
    __shared__ float actb[128];
    const int wg = blockIdx.x;
    const int dir = wg >> 3;        // 0 fwd, 1 bwd
    const int wi = wg & 7;          // index within direction
    const int ub = wi * 32;         // first hidden unit owned
    const int tid = threadIdx.x;
    const int kg = tid >> 4;        // 0..15  k-slice (16 wide)
    const int rg = tid & 15;        // 0..15  row group (8 rows each)
    const int k0 = kg * 16;
    const float* Whh = dir ? Whh_b : Whh_f;

    // load weights into registers: 8 rows x 16 k
    float w[8][16];
#pragma unroll
    for (int q = 0; q < 8; ++q) {
        const int lr = rg * 8 + q;                      // 0..127
        const int grow = (lr >> 5) * 256 + ub + (lr & 31);
        const float* wr = Whh + (size_t)grow * 256 + k0;
#pragma unroll
        for (int kk = 0; kk < 16; kk += 4) {
            float4 v = *(const float4*)(wr + kk);
            w[q][kk] = v.x; w[q][kk + 1] = v.y; w[q][kk + 2] = v.z; w[q][kk + 3] = v.w;
        }
    }
#pragma unroll
    for (int q = 0; q < 8; ++q)
#pragma unroll
        for (int kk = 0; kk < 16; ++kk)
            asm volatile("" : "+v"(w[q][kk]));   // keep register-resident

    // seed cell state and {h0, tag=0} for this WG's own units
    float cst = 0.f;
    if (tid < 32) {
        cst = c0[dir * 256 + ub + tid];
        uint2 iv;
        iv.x = __float_as_uint(h0[dir * 256 + ub + tid]);
        iv.y = 0u;
        st_pair_dev(hcur2 + (size_t)dir * 256 + ub + tid, iv);   // slot 0
    }
    // z-row mapping for tid<128: row = tid -> gate=tid>>5, unit=tid&31
    const int zcol = dir * 1024 + (tid >> 5) * 256 + ub + (tid & 31);

    for (int step = 0; step < S; ++step) {
        // prefetch input part (plain cached load; overlaps the poll)
        float xzv = 0.f;
        if (tid < 128) {
            const int tz = dir ? (S - 1 - step) : step;
            xzv = xz[(size_t)tz * NCOL + zcol];
        }
        // poll the data itself: 16 {h, tag} pairs of this k-slice
        const uint2* hb = hcur2 + ((size_t)(step & 1) * 2 + dir) * 256 + k0;
        float h16[16];
        while (!try_h16(hb, (unsigned)step, h16)) {}

        float acc[8];
#pragma unroll
        for (int q = 0; q < 8; ++q) acc[q] = 0.f;
#pragma unroll
        for (int kk = 0; kk < 16; ++kk)
#pragma unroll
            for (int q = 0; q < 8; ++q) acc[q] += w[q][kk] * h16[kk];
        // butterfly over the 4 k-groups within this wave
#pragma unroll
        for (int q = 0; q < 8; ++q) {
            acc[q] += __shfl_xor(acc[q], 16);
            acc[q] += __shfl_xor(acc[q], 32);
        }
        if ((kg & 3) == 0) {
            const int wv = kg >> 2;
#pragma unroll
            for (int q = 0; q < 8; ++q) red[wv][rg][q] = acc[q];
        }
        __syncthreads();
        if (tid < 128) {
            const int rg2 = tid >> 3, q2 = tid & 7;
            const float z = ((red[0][rg2][q2] + red[1][rg2][q2]) +
                             (red[2][rg2][q2] + red[3][rg2][q2])) + xzv;
            const int gate = tid >> 5;
            actb[tid] = (gate == 2) ? tanhf(z) : (1.f / (1.f + expf(-z)));
        }
        __syncthreads();
        if (tid < 32) {
            const int u = tid;
            const float ig = actb[u];
            const float fg = actb[32 + u];
            const float gg = actb[64 + u];
            const float og = actb[96 + u];
            cst = fg * cst + ig * gg;
            const float h = og * tanhf(cst);
            const int tz = dir ? (S - 1 - step) : step;
            uint2 pv;
            pv.x = __float_as_uint(h);
            pv.y = (unsigned)(step + 1);
            st_pair_dev(hcur2 + ((size_t)((step + 1) & 1) * 2 + dir) * 256 + ub + u, pv);
            lstm_out[(size_t)tz * 512 + dir * 256 + ub + u] = h;   // plain store
        }
    }
}

// =========================================================
// Kernel 3: feats[t][tag] = lstm_out[t] . W_out[tag] + b_out[tag]
// (unchanged, proven)
// =========================================================
__global__ __launch_bounds__(256) void feats_k(
    const float* __restrict__ lstm, const float* __restrict__ Wout,
    const float* __restrict__ bout, float* __restrict__ feats)
{
    const int gid = blockIdx.x * 256 + threadIdx.x;
    if (gid >= S * NT) return;
    const int t = gid / NT, tag = gid - t * NT;
    const float* hr = lstm + (size_t)t * 512;
    const float* wr = Wout + (size_t)tag * 512;
    float s0 = 0, s1 = 0, s2 = 0, s3 = 0;
#pragma unroll 4
    for (int k = 0; k < 512; k += 4) {
        float4 h4 = *(const float4*)(hr + k);
        float4 w4 = *(const float4*)(wr + k);
        s0 += h4.x * w4.x; s1 += h4.y * w4.y;
        s2 += h4.z * w4.z; s3 += h4.w * w4.w;
    }
    feats[gid] = (s0 + s1) + (s2 + s3) + bout[tag];
}

// =========================================================
// Kernel 4: Viterbi, v5 forward: single wave, zero LDS, zero barrier
// (r14 proven) + DISTANCE-4 OBS PREFETCH. The r14 step body (~200 cy)
// could not hide the serial feats load (~200-850 cy); unrolling by 4
// with two register banks issues next-block loads before processing
// the current block from registers -> load latency fully covered.
// Per-step computation identical values/order to r14 (only obs
// sourcing changes) -> bit-identical output. Tail: prefetch indices
// clamped to S-1 (values unused), uniform t<S guard.
// =========================================================
__global__ void __launch_bounds__(256, 1) viterbi_k(
    const float* __restrict__ feats, const float* __restrict__ trans,
    unsigned char* __restrict__ bps, unsigned char* __restrict__ pathA,
    int* __restrict__ out)
{
    __shared__ unsigned char cmap[64][NT];
    __shared__ int SB[65];
    __shared__ int last_s;
    const int tid = threadIdx.x;

    if (tid < 64) {
        const bool actj = tid < NT;
        const int j = actj ? tid : 0;
        // trans column in registers (static indices only)
        float T[NT];
#pragma unroll
        for (int i = 0; i < NT; ++i) T[i] = trans[i * NT + j];
        float vself = feats[j];            // v at t=0

        auto STEP = [&](int t, float obs) {
            float b0 = -1e30f, b1 = -1e30f, b2 = -1e30f, b3 = -1e30f;
            int i0 = 0, i1 = 12, i2 = 24, i3 = 36;
#pragma unroll
            for (int r = 0; r < 12; ++r) {
                const float v0 = __shfl(vself, r);
                const float v1 = __shfl(vself, 12 + r);
                const float v2 = __shfl(vself, 24 + r);
                const float v3 = __shfl(vself, 36 + r);
                const float s0 = (v0 + T[r])      + obs;
                const float s1 = (v1 + T[12 + r]) + obs;
                const float s2 = (v2 + T[24 + r]) + obs;
                const float s3 = (v3 + T[36 + r]) + obs;
                if (s0 > b0) { b0 = s0; i0 = r; }
                if (s1 > b1) { b1 = s1; i1 = 12 + r; }
                if (s2 > b2) { b2 = s2; i2 = 24 + r; }
                if (s3 > b3) { b3 = s3; i3 = 36 + r; }
            }
            float best = b0; int bi = i0;
            if (b1 > best) { best = b1; bi = i1; }
            if (b2 > best) { best = b2; bi = i2; }
            if (b3 > best) { best = b3; bi = i3; }
            if (actj) {
                bps[(size_t)(t - 1) * NT + j] = (unsigned char)bi;
                vself = best;
            }
        };

        // preload obs for t = 1..4
        float o0 = feats[(size_t)1 * NT + j];
        float o1 = feats[(size_t)2 * NT + j];
        float o2 = feats[(size_t)3 * NT + j];
        float o3 = feats[(size_t)4 * NT + j];

        for (int tb = 1; tb < S; tb += 4) {
            // issue next block's obs loads (independent; hoists above STEPs)
            const int p0 = (tb + 4 < S) ? (tb + 4) : (S - 1);
            const int p1 = (tb + 5 < S) ? (tb + 5) : (S - 1);
            const int p2 = (tb + 6 < S) ? (tb + 6) : (S - 1);
            const int p3 = (tb + 7 < S) ? (tb + 7) : (S - 1);
            const float n0 = feats[(size_t)p0 * NT + j];
            const float n1 = feats[(size_t)p1 * NT + j];
            const float n2 = feats[(size_t)p2 * NT + j];
            const float n3 = feats[(size_t)p3 * NT + j];

            STEP(tb + 0, o0);
            if (tb + 1 < S) STEP(tb + 1, o1);
            if (tb + 2 < S) STEP(tb + 2, o2);
            if (tb + 3 < S) STEP(tb + 3, o3);

            o0 = n0; o1 = n1; o2 = n2; o3 = n3;
        }
        // final argmax across lanes (first occurrence), via readlane
        {
            float b = __shfl(vself, 0); int bi = 0;
#pragma unroll
            for (int q = 1; q < NT; ++q) {
                const float vq = __shfl(vself, q);
                if (vq > b) { b = vq; bi = q; }
            }
            if (tid == 0) last_s = bi;
        }
    }
    __syncthreads();

    // Phase A: 64 chunks x 48 states, 12 tasks/thread, ILP-12 chains
    int cArr[12], sArr[12];
    unsigned char stv[12];
#pragma unroll
    for (int r = 0; r < 12; ++r) {
        const int task = r * 256 + tid;
        cArr[r] = task / NT;
        sArr[r] = task - cArr[r] * NT;
        stv[r] = (unsigned char)sArr[r];
    }
    for (int stp = 31; stp >= 0; --stp) {
#pragma unroll
        for (int r = 0; r < 12; ++r) {
            const int km = cArr[r] * 32 + stp;
            if (km < S - 1) stv[r] = bps[(size_t)km * NT + stv[r]];
            pathA[(size_t)(cArr[r] * NT + sArr[r]) * 32 + stp] = stv[r];
        }
    }
#pragma unroll
    for (int r = 0; r < 12; ++r) cmap[cArr[r]][sArr[r]] = stv[r];
    __syncthreads();
    if (tid == 0) {
        SB[64] = last_s;
        for (int c = 63; c >= 0; --c) SB[c] = cmap[c][SB[c + 1]];
    }
    __syncthreads();
    for (int t = tid; t < S; t += 256) {
        const int c = t >> 5;
        out[t] = (int)pathA[(size_t)(c * NT + SB[c + 1]) * 32 + (t & 31)];
    }
}

// =========================================================
extern "C" void kernel_launch(void* const* d_in, const int* in_sizes, int n_in,
                              void* d_out, int out_size, void* d_ws, size_t ws_size,
                              hipStream_t stream) {
    const int*   sent   = (const int*)d_in[0];
    const float* emb    = (const float*)d_in[1];
    const float* Wih_f  = (const float*)d_in[2];
    const float* Whh_f  = (const float*)d_in[3];
    const float* b_f    = (const float*)d_in[4];
    const float* Wih_b  = (const float*)d_in[5];
    const float* Whh_b  = (const float*)d_in[6];
    const float* b_b    = (const float*)d_in[7];
    const float* W_out  = (const float*)d_in[8];
    const float* b_out  = (const float*)d_in[9];
    const float* trans  = (const float*)d_in[10];
    const float* h0     = (const float*)d_in[11];
    const float* c0     = (const float*)d_in[12];
    int* out = (int*)d_out;

    char* ws = (char*)d_ws;
    float* xz       = (float*)(ws + XZ_OFF);
    float* lstm     = (float*)(ws + LSTM_OFF);
    float* feats    = (float*)(ws + FEATS_OFF);
    uint2* hcur2    = (uint2*)(ws + HCUR2_OFF);
    unsigned char* bps   = (unsigned char*)(ws + BPS_OFF);
    unsigned char* pathA = (unsigned char*)(ws + PATHA_OFF);

    // reset tags so no stale {h, tag} pair from a previous replay can
    // alias a wanted tag (tags are exact-match, 0..2048)
    hipMemsetAsync(hcur2, 0xFF, HCUR2_BYTES, stream);

    gemm_xz<<<dim3(16, 16), 256, 0, stream>>>(sent, emb, Wih_f, Wih_b, b_f, b_b, xz);

    lstm_rec<<<dim3(NWG), 256, 0, stream>>>(Whh_f, Whh_b, h0, c0, xz, hcur2, lstm);

    feats_k<<<dim3((S * NT + 255) / 256), 256, 0, stream>>>(lstm, W_out, b_out, feats);

    viterbi_k<<<dim3(1), 256, 0, stream>>>(feats, trans, bps, pathA, out);
}